// Round 1
// baseline (343.002 us; speedup 1.0000x reference)
//
#include <hip/hip_runtime.h>

#define DD 64

// ---------------------------------------------------------------------------
// Pass 1: zero h_mask / relevant / count
__global__ void k_zero(int* __restrict__ h_mask, int* __restrict__ relevant,
                       int* __restrict__ count, int N) {
    int i = blockIdx.x * blockDim.x + threadIdx.x;
    if (i == 0) *count = 0;
    if (i < N) { h_mask[i] = 0; relevant[i] = 0; }
}

// Pass 2: rel_ctx = mean over R rows; set h_mask/relevant for query nodes.
__global__ void k_ctx_hmask(const float* __restrict__ rel, int R,
                            const int* __restrict__ h_index, int B,
                            float* __restrict__ ctx, int* __restrict__ h_mask,
                            int* __restrict__ relevant) {
    int t = threadIdx.x;
    if (t < DD) {
        float s = 0.f;
        for (int r = 0; r < R; ++r) s += rel[(size_t)r * DD + t];
        ctx[t] = s / (float)R;
    }
    if (t < B) {
        int n = h_index[t];
        h_mask[n] = 1;
        relevant[n] = 1;
    }
}

// Pass 3: mark 1-hop neighbors of query nodes as relevant.
__global__ void k_mark(const int* __restrict__ src, const int* __restrict__ dst,
                       const int* __restrict__ h_mask, int* __restrict__ relevant,
                       int E) {
    int i = blockIdx.x * blockDim.x + threadIdx.x;
    int e = i * 4;
    if (e + 3 < E) {
        int4 s4 = *(const int4*)(src + e);
        int4 d4 = *(const int4*)(dst + e);
        if (h_mask[s4.x]) relevant[d4.x] = 1;
        if (h_mask[d4.x]) relevant[s4.x] = 1;
        if (h_mask[s4.y]) relevant[d4.y] = 1;
        if (h_mask[d4.y]) relevant[s4.y] = 1;
        if (h_mask[s4.z]) relevant[d4.z] = 1;
        if (h_mask[d4.z]) relevant[s4.z] = 1;
        if (h_mask[s4.w]) relevant[d4.w] = 1;
        if (h_mask[d4.w]) relevant[s4.w] = 1;
    } else {
        for (; e < E; ++e) {
            int s = src[e], d = dst[e];
            if (h_mask[s]) relevant[d] = 1;
            if (h_mask[d]) relevant[s] = 1;
        }
    }
}

// Pass 4: compact relevant node list; zero their accumulators.
__global__ void k_compact(const int* __restrict__ relevant, int* __restrict__ rel_list,
                          int* __restrict__ count, unsigned* __restrict__ cnt,
                          unsigned* __restrict__ nbr, float* __restrict__ feat, int N) {
    int n = blockIdx.x * blockDim.x + threadIdx.x;
    if (n >= N) return;
    if (relevant[n]) {
        int slot = atomicAdd(count, 1);
        rel_list[slot] = n;
        cnt[n] = 0u;
        nbr[n] = 0u;
        float4 z = make_float4(0.f, 0.f, 0.f, 0.f);
        float4* f = (float4*)(feat + (size_t)n * DD);
#pragma unroll
        for (int q = 0; q < DD / 4; ++q) f[q] = z;
    }
}

// Pass 5: edge accumulation for relevant endpoints only.
//   feat[src] += rel[t]           cnt[src] += 1        nbr[src] += w
//   feat[dst] += w * rel[t]       cnt[dst] += w        nbr[dst] += w     (w = src!=dst)
__device__ __forceinline__ void accum_edge(int s, int d, int t,
                                           const int* __restrict__ relevant,
                                           const float* __restrict__ rel,
                                           float* __restrict__ feat,
                                           unsigned* __restrict__ cnt,
                                           unsigned* __restrict__ nbr) {
    int rs = relevant[s];
    int rd = relevant[d];
    if (!(rs | rd)) return;
    int w = (s != d) ? 1 : 0;
    const float* rrow = rel + (size_t)t * DD;
    if (rs) {
        float* fs = feat + (size_t)s * DD;
#pragma unroll 8
        for (int q = 0; q < DD; ++q) atomicAdd(fs + q, rrow[q]);
        atomicAdd(cnt + s, 1u);
        if (w) atomicAdd(nbr + s, 1u);
    }
    if (rd && w) {
        float* fd = feat + (size_t)d * DD;
#pragma unroll 8
        for (int q = 0; q < DD; ++q) atomicAdd(fd + q, rrow[q]);
        atomicAdd(cnt + d, 1u);
        atomicAdd(nbr + d, 1u);
    }
}

__global__ void k_accum(const int* __restrict__ src, const int* __restrict__ dst,
                        const int* __restrict__ etype, const int* __restrict__ relevant,
                        const float* __restrict__ rel, float* __restrict__ feat,
                        unsigned* __restrict__ cnt, unsigned* __restrict__ nbr, int E) {
    int i = blockIdx.x * blockDim.x + threadIdx.x;
    int e = i * 4;
    if (e + 3 < E) {
        int4 s4 = *(const int4*)(src + e);
        int4 d4 = *(const int4*)(dst + e);
        // Fast common path: nothing relevant among the 8 endpoints.
        int any = relevant[s4.x] | relevant[d4.x] | relevant[s4.y] | relevant[d4.y] |
                  relevant[s4.z] | relevant[d4.z] | relevant[s4.w] | relevant[d4.w];
        if (!any) return;
        accum_edge(s4.x, d4.x, etype[e + 0], relevant, rel, feat, cnt, nbr);
        accum_edge(s4.y, d4.y, etype[e + 1], relevant, rel, feat, cnt, nbr);
        accum_edge(s4.z, d4.z, etype[e + 2], relevant, rel, feat, cnt, nbr);
        accum_edge(s4.w, d4.w, etype[e + 3], relevant, rel, feat, cnt, nbr);
    } else {
        for (; e < E; ++e)
            accum_edge(src[e], dst[e], etype[e], relevant, rel, feat, cnt, nbr);
    }
}

// Pass 6: per relevant node: avg -> MLP -> final, written in place into feat.
__global__ __launch_bounds__(64) void k_mlp(
    const int* __restrict__ rel_list, const int* __restrict__ count,
    const unsigned* __restrict__ cnt, const unsigned* __restrict__ nbr,
    const float* __restrict__ ctx,
    const float* __restrict__ Wi1, const float* __restrict__ bi1,
    const float* __restrict__ Wi2, const float* __restrict__ bi2,
    const float* __restrict__ Wc1, const float* __restrict__ bc1,
    const float* __restrict__ Wc2, const float* __restrict__ bc2,
    const float* __restrict__ strength, float* __restrict__ feat) {
    int j = threadIdx.x;   // 64 lanes = one wave per node
    int C = *count;
    float alpha = fminf(fmaxf(strength[0], 0.f), 0.3f);
    float ctxj = ctx[j];
    for (int i = blockIdx.x; i < C; i += gridDim.x) {
        int n = rel_list[i];
        float* frow = feat + (size_t)n * DD;
        unsigned c = cnt[n];
        if (c == 0u) {              // relevant but no incident edges -> rel_ctx
            frow[j] = ctxj;
            continue;
        }
        float avg = frow[j] / (float)c;
        bool hasnbr = (nbr[n] > 0u);  // wave-uniform
        const float* W1 = hasnbr ? Wc1 : Wi1;
        const float* b1 = hasnbr ? bc1 : bi1;
        const float* W2 = hasnbr ? Wc2 : Wi2;
        const float* b2 = hasnbr ? bc2 : bi2;
        // x = [avg, hasnbr ? avg : ctx]  (context uses [avg,avg]; interaction [avg,ctx])
        float h1 = b1[j];
#pragma unroll 4
        for (int k = 0; k < DD; ++k) {
            float a_k = __shfl(avg, k);
            float x2  = hasnbr ? a_k : __shfl(ctxj, k);
            h1 += a_k * W1[k * DD + j] + x2 * W1[(DD + k) * DD + j];
        }
        h1 = fmaxf(h1, 0.f);
        float out = b2[j];
#pragma unroll 4
        for (int k = 0; k < DD; ++k)
            out += __shfl(h1, k) * W2[k * DD + j];
        frow[j] = (1.f - alpha) * avg + alpha * out;
    }
}

// Pass 7: write [B, N, D] output; zeros for non-relevant rows; B broadcast copies.
__global__ void k_out(const int* __restrict__ relevant, const float* __restrict__ feat,
                      float* __restrict__ out, int N, int B) {
    int idx = blockIdx.x * blockDim.x + threadIdx.x;
    int total = N * (DD / 4);
    if (idx >= total) return;
    int n = idx >> 4;
    int q = idx & 15;
    float4 v = make_float4(0.f, 0.f, 0.f, 0.f);
    if (relevant[n]) v = *(const float4*)(feat + (size_t)n * DD + q * 4);
    size_t plane = (size_t)N * DD;
    float* p = out + (size_t)n * DD + (size_t)q * 4;
    for (int b = 0; b < B; ++b)
        *(float4*)(p + (size_t)b * plane) = v;
}

extern "C" void kernel_launch(void* const* d_in, const int* in_sizes, int n_in,
                              void* d_out, int out_size, void* d_ws, size_t ws_size,
                              hipStream_t stream) {
    const int*   edge_index = (const int*)d_in[0];    // [2, E]
    const int*   edge_type  = (const int*)d_in[1];    // [E]
    const int*   h_index    = (const int*)d_in[2];    // [B]
    const float* rel_emb    = (const float*)d_in[3];  // [R, 64]
    const float* Wi1 = (const float*)d_in[5];
    const float* bi1 = (const float*)d_in[6];
    const float* Wi2 = (const float*)d_in[7];
    const float* bi2 = (const float*)d_in[8];
    const float* Wc1 = (const float*)d_in[9];
    const float* bc1 = (const float*)d_in[10];
    const float* Wc2 = (const float*)d_in[11];
    const float* bc2 = (const float*)d_in[12];
    const float* strength = (const float*)d_in[13];
    float* out = (float*)d_out;

    const int E = in_sizes[1];
    const int B = in_sizes[2];
    const int R = in_sizes[3] / DD;
    const int N = out_size / (B * DD);
    const int* src = edge_index;
    const int* dst = edge_index + E;

    // workspace carve-up (256B-aligned slots)
    char* w = (char*)d_ws;
    size_t off = 0;
    auto carve = [&](size_t bytes) -> char* {
        char* p = w + off;
        off += (bytes + 255) & ~(size_t)255;
        return p;
    };
    float*    ctx      = (float*)carve(DD * sizeof(float));
    int*      count    = (int*)carve(sizeof(int));
    int*      h_mask   = (int*)carve((size_t)N * sizeof(int));
    int*      relevant = (int*)carve((size_t)N * sizeof(int));
    unsigned* cnt      = (unsigned*)carve((size_t)N * sizeof(unsigned));
    unsigned* nbr      = (unsigned*)carve((size_t)N * sizeof(unsigned));
    int*      rel_list = (int*)carve((size_t)N * sizeof(int));
    float*    feat     = (float*)carve((size_t)N * DD * sizeof(float));
    (void)ws_size; (void)n_in;

    const int BLK = 256;
    int gN  = (N + BLK - 1) / BLK;
    int gE4 = ((E + 3) / 4 + BLK - 1) / BLK;
    int gO  = (N * (DD / 4) + BLK - 1) / BLK;

    hipLaunchKernelGGL(k_zero, dim3(gN), dim3(BLK), 0, stream, h_mask, relevant, count, N);
    hipLaunchKernelGGL(k_ctx_hmask, dim3(1), dim3(64), 0, stream,
                       rel_emb, R, h_index, B, ctx, h_mask, relevant);
    hipLaunchKernelGGL(k_mark, dim3(gE4), dim3(BLK), 0, stream, src, dst, h_mask, relevant, E);
    hipLaunchKernelGGL(k_compact, dim3(gN), dim3(BLK), 0, stream,
                       relevant, rel_list, count, cnt, nbr, feat, N);
    hipLaunchKernelGGL(k_accum, dim3(gE4), dim3(BLK), 0, stream,
                       src, dst, edge_type, relevant, rel_emb, feat, cnt, nbr, E);
    hipLaunchKernelGGL(k_mlp, dim3(512), dim3(64), 0, stream,
                       rel_list, count, cnt, nbr, ctx,
                       Wi1, bi1, Wi2, bi2, Wc1, bc1, Wc2, bc2, strength, feat);
    hipLaunchKernelGGL(k_out, dim3(gO), dim3(BLK), 0, stream, relevant, feat, out, N, B);
}

// Round 2
// 185.002 us; speedup vs baseline: 1.8540x; 1.8540x over previous
//
#include <hip/hip_runtime.h>

#define DD 64

typedef float f4v __attribute__((ext_vector_type(4)));

// ---------------------------------------------------------------------------
// Pass 1: zero relevant / bitmap / count
__global__ void k_zero(int* __restrict__ relevant, unsigned* __restrict__ bitmap,
                       int* __restrict__ count, int N, int NB) {
    int i = blockIdx.x * blockDim.x + threadIdx.x;
    if (i == 0) *count = 0;
    if (i < N) relevant[i] = 0;
    if (i < NB) bitmap[i] = 0u;
}

// Pass 2: rel_ctx = mean over R rows (8 waves, coalesced); mark query nodes.
__global__ __launch_bounds__(512) void k_ctx(const float* __restrict__ rel, int R,
                                             const int* __restrict__ h_index, int B,
                                             float* __restrict__ ctx,
                                             int* __restrict__ relevant) {
    __shared__ float part[8][DD];
    int lane = threadIdx.x & 63;
    int w = threadIdx.x >> 6;
    float s0 = 0.f, s1 = 0.f;
    // two independent accumulators to deepen the load pipeline
    int r = w;
    for (; r + 16 <= R; r += 16) {
        s0 += rel[(size_t)r * DD + lane];
        s1 += rel[(size_t)(r + 8) * DD + lane];
    }
    for (; r < R; r += 8) s0 += rel[(size_t)r * DD + lane];
    part[w][lane] = s0 + s1;
    __syncthreads();
    int t = threadIdx.x;
    if (t < DD) {
        float tot = 0.f;
#pragma unroll
        for (int i = 0; i < 8; ++i) tot += part[i][t];
        ctx[t] = tot / (float)R;
    }
    if (t < B) relevant[h_index[t]] = 1;
}

// Pass 3: mark 1-hop neighbors of query nodes (compare vs B ids in LDS —
// no scattered global gathers).
__global__ void k_mark(const int* __restrict__ src, const int* __restrict__ dst,
                       const int* __restrict__ h_index, int B,
                       int* __restrict__ relevant, int E) {
    __shared__ int hs[64];
    if (threadIdx.x < B) hs[threadIdx.x] = h_index[threadIdx.x];
    __syncthreads();
    int i = blockIdx.x * blockDim.x + threadIdx.x;
    int e = i * 4;
    if (e + 3 < E) {
        int4 s4 = *(const int4*)(src + e);
        int4 d4 = *(const int4*)(dst + e);
        for (int b = 0; b < B; ++b) {
            int h = hs[b];
            if (s4.x == h) relevant[d4.x] = 1;
            if (d4.x == h) relevant[s4.x] = 1;
            if (s4.y == h) relevant[d4.y] = 1;
            if (d4.y == h) relevant[s4.y] = 1;
            if (s4.z == h) relevant[d4.z] = 1;
            if (d4.z == h) relevant[s4.z] = 1;
            if (s4.w == h) relevant[d4.w] = 1;
            if (d4.w == h) relevant[s4.w] = 1;
        }
    } else {
        for (; e < E; ++e) {
            int s = src[e], d = dst[e];
            for (int b = 0; b < B; ++b) {
                int h = hs[b];
                if (s == h) relevant[d] = 1;
                if (d == h) relevant[s] = 1;
            }
        }
    }
}

// Pass 4: compact relevant node list; build bitmap; zero accumulators.
__global__ void k_compact(const int* __restrict__ relevant, int* __restrict__ rel_list,
                          int* __restrict__ count, unsigned* __restrict__ bitmap,
                          unsigned* __restrict__ cnt, unsigned* __restrict__ nbr,
                          float* __restrict__ feat, int N) {
    int n = blockIdx.x * blockDim.x + threadIdx.x;
    if (n >= N) return;
    if (relevant[n]) {
        int slot = atomicAdd(count, 1);
        rel_list[slot] = n;
        atomicOr(bitmap + (n >> 5), 1u << (n & 31));
        cnt[n] = 0u;
        nbr[n] = 0u;
        float4 z = make_float4(0.f, 0.f, 0.f, 0.f);
        float4* f = (float4*)(feat + (size_t)n * DD);
#pragma unroll
        for (int q = 0; q < DD / 4; ++q) f[q] = z;
    }
}

// Pass 5: edge accumulation; relevance test via LDS-resident bitmap.
__device__ __forceinline__ void accum_edge(int s, int d, int t, int rs, int rd,
                                           const float* __restrict__ rel,
                                           float* __restrict__ feat,
                                           unsigned* __restrict__ cnt,
                                           unsigned* __restrict__ nbr) {
    if (!(rs | rd)) return;
    int w = (s != d) ? 1 : 0;
    const float* rrow = rel + (size_t)t * DD;
    if (rs) {
        float* fs = feat + (size_t)s * DD;
#pragma unroll 8
        for (int q = 0; q < DD; ++q) atomicAdd(fs + q, rrow[q]);
        atomicAdd(cnt + s, 1u);
        if (w) atomicAdd(nbr + s, 1u);
    }
    if (rd && w) {
        float* fd = feat + (size_t)d * DD;
#pragma unroll 8
        for (int q = 0; q < DD; ++q) atomicAdd(fd + q, rrow[q]);
        atomicAdd(cnt + d, 1u);
        atomicAdd(nbr + d, 1u);
    }
}

__global__ void k_accum(const int* __restrict__ src, const int* __restrict__ dst,
                        const int* __restrict__ etype,
                        const unsigned* __restrict__ bitmap, int NB,
                        const float* __restrict__ rel, float* __restrict__ feat,
                        unsigned* __restrict__ cnt, unsigned* __restrict__ nbr, int E) {
    extern __shared__ unsigned bm[];
    for (int i = threadIdx.x; i < NB; i += blockDim.x) bm[i] = bitmap[i];
    __syncthreads();
    int i = blockIdx.x * blockDim.x + threadIdx.x;
    int e = i * 4;
    if (e + 3 < E) {
        int4 s4 = *(const int4*)(src + e);
        int4 d4 = *(const int4*)(dst + e);
        unsigned rsx = (bm[s4.x >> 5] >> (s4.x & 31)) & 1u;
        unsigned rdx = (bm[d4.x >> 5] >> (d4.x & 31)) & 1u;
        unsigned rsy = (bm[s4.y >> 5] >> (s4.y & 31)) & 1u;
        unsigned rdy = (bm[d4.y >> 5] >> (d4.y & 31)) & 1u;
        unsigned rsz = (bm[s4.z >> 5] >> (s4.z & 31)) & 1u;
        unsigned rdz = (bm[d4.z >> 5] >> (d4.z & 31)) & 1u;
        unsigned rsw = (bm[s4.w >> 5] >> (s4.w & 31)) & 1u;
        unsigned rdw = (bm[d4.w >> 5] >> (d4.w & 31)) & 1u;
        if (!(rsx | rdx | rsy | rdy | rsz | rdz | rsw | rdw)) return;
        accum_edge(s4.x, d4.x, etype[e + 0], rsx, rdx, rel, feat, cnt, nbr);
        accum_edge(s4.y, d4.y, etype[e + 1], rsy, rdy, rel, feat, cnt, nbr);
        accum_edge(s4.z, d4.z, etype[e + 2], rsz, rdz, rel, feat, cnt, nbr);
        accum_edge(s4.w, d4.w, etype[e + 3], rsw, rdw, rel, feat, cnt, nbr);
    } else {
        for (; e < E; ++e) {
            int s = src[e], d = dst[e];
            unsigned rs = (bm[s >> 5] >> (s & 31)) & 1u;
            unsigned rd = (bm[d >> 5] >> (d & 31)) & 1u;
            if (rs | rd) accum_edge(s, d, etype[e], rs, rd, rel, feat, cnt, nbr);
        }
    }
}

// Pass 6: per relevant node: avg -> MLP -> final, written in place into feat.
__global__ __launch_bounds__(64) void k_mlp(
    const int* __restrict__ rel_list, const int* __restrict__ count,
    const unsigned* __restrict__ cnt, const unsigned* __restrict__ nbr,
    const float* __restrict__ ctx,
    const float* __restrict__ Wi1, const float* __restrict__ bi1,
    const float* __restrict__ Wi2, const float* __restrict__ bi2,
    const float* __restrict__ Wc1, const float* __restrict__ bc1,
    const float* __restrict__ Wc2, const float* __restrict__ bc2,
    const float* __restrict__ strength, float* __restrict__ feat) {
    int j = threadIdx.x;   // 64 lanes = one wave per node
    int C = *count;
    float alpha = fminf(fmaxf(strength[0], 0.f), 0.3f);
    float ctxj = ctx[j];
    for (int i = blockIdx.x; i < C; i += gridDim.x) {
        int n = rel_list[i];
        float* frow = feat + (size_t)n * DD;
        unsigned c = cnt[n];
        if (c == 0u) {              // relevant but no incident edges -> rel_ctx
            frow[j] = ctxj;
            continue;
        }
        float avg = frow[j] / (float)c;
        bool hasnbr = (nbr[n] > 0u);  // wave-uniform
        const float* W1 = hasnbr ? Wc1 : Wi1;
        const float* b1 = hasnbr ? bc1 : bi1;
        const float* W2 = hasnbr ? Wc2 : Wi2;
        const float* b2 = hasnbr ? bc2 : bi2;
        // x = [avg, hasnbr ? avg : ctx]  (context: [avg,avg]; interaction: [avg,ctx])
        float h1 = b1[j];
#pragma unroll 4
        for (int k = 0; k < DD; ++k) {
            float a_k = __shfl(avg, k);
            float x2  = hasnbr ? a_k : __shfl(ctxj, k);
            h1 += a_k * W1[k * DD + j] + x2 * W1[(DD + k) * DD + j];
        }
        h1 = fmaxf(h1, 0.f);
        float out = b2[j];
#pragma unroll 4
        for (int k = 0; k < DD; ++k)
            out += __shfl(h1, k) * W2[k * DD + j];
        frow[j] = (1.f - alpha) * avg + alpha * out;
    }
}

// Pass 7: write [B, N, D] output; zeros for non-relevant rows; B planes.
__global__ void k_out(const int* __restrict__ relevant, const float* __restrict__ feat,
                      float* __restrict__ out, int N, int B) {
    int idx = blockIdx.x * blockDim.x + threadIdx.x;
    int total = N * (DD / 4);
    if (idx >= total) return;
    int n = idx >> 4;
    int q = idx & 15;
    f4v v = (f4v)(0.f);
    if (relevant[n]) v = *(const f4v*)(feat + (size_t)n * DD + q * 4);
    size_t plane = (size_t)N * DD;
    float* p = out + (size_t)n * DD + (size_t)q * 4;
    for (int b = 0; b < B; ++b)
        __builtin_nontemporal_store(v, (f4v*)(p + (size_t)b * plane));
}

extern "C" void kernel_launch(void* const* d_in, const int* in_sizes, int n_in,
                              void* d_out, int out_size, void* d_ws, size_t ws_size,
                              hipStream_t stream) {
    const int*   edge_index = (const int*)d_in[0];    // [2, E]
    const int*   edge_type  = (const int*)d_in[1];    // [E]
    const int*   h_index    = (const int*)d_in[2];    // [B]
    const float* rel_emb    = (const float*)d_in[3];  // [R, 64]
    const float* Wi1 = (const float*)d_in[5];
    const float* bi1 = (const float*)d_in[6];
    const float* Wi2 = (const float*)d_in[7];
    const float* bi2 = (const float*)d_in[8];
    const float* Wc1 = (const float*)d_in[9];
    const float* bc1 = (const float*)d_in[10];
    const float* Wc2 = (const float*)d_in[11];
    const float* bc2 = (const float*)d_in[12];
    const float* strength = (const float*)d_in[13];
    float* out = (float*)d_out;

    const int E = in_sizes[1];
    const int B = in_sizes[2];
    const int R = in_sizes[3] / DD;
    const int N = out_size / (B * DD);
    const int NB = (N + 31) / 32;      // bitmap words
    const int* src = edge_index;
    const int* dst = edge_index + E;

    // workspace carve-up (256B-aligned slots)
    char* w = (char*)d_ws;
    size_t off = 0;
    auto carve = [&](size_t bytes) -> char* {
        char* p = w + off;
        off += (bytes + 255) & ~(size_t)255;
        return p;
    };
    float*    ctx      = (float*)carve(DD * sizeof(float));
    int*      count    = (int*)carve(sizeof(int));
    int*      relevant = (int*)carve((size_t)N * sizeof(int));
    unsigned* bitmap   = (unsigned*)carve((size_t)NB * sizeof(unsigned));
    unsigned* cnt      = (unsigned*)carve((size_t)N * sizeof(unsigned));
    unsigned* nbr      = (unsigned*)carve((size_t)N * sizeof(unsigned));
    int*      rel_list = (int*)carve((size_t)N * sizeof(int));
    float*    feat     = (float*)carve((size_t)N * DD * sizeof(float));
    (void)ws_size; (void)n_in;

    const int BLK = 256;
    int gN  = (N + BLK - 1) / BLK;
    int gE4 = ((E + 3) / 4 + BLK - 1) / BLK;
    int gO  = (N * (DD / 4) + BLK - 1) / BLK;

    hipLaunchKernelGGL(k_zero, dim3(gN), dim3(BLK), 0, stream,
                       relevant, bitmap, count, N, NB);
    hipLaunchKernelGGL(k_ctx, dim3(1), dim3(512), 0, stream,
                       rel_emb, R, h_index, B, ctx, relevant);
    hipLaunchKernelGGL(k_mark, dim3(gE4), dim3(BLK), 0, stream,
                       src, dst, h_index, B, relevant, E);
    hipLaunchKernelGGL(k_compact, dim3(gN), dim3(BLK), 0, stream,
                       relevant, rel_list, count, bitmap, cnt, nbr, feat, N);
    hipLaunchKernelGGL(k_accum, dim3(gE4), dim3(BLK), (size_t)NB * sizeof(unsigned), stream,
                       src, dst, edge_type, bitmap, NB, rel_emb, feat, cnt, nbr, E);
    hipLaunchKernelGGL(k_mlp, dim3(512), dim3(64), 0, stream,
                       rel_list, count, cnt, nbr, ctx,
                       Wi1, bi1, Wi2, bi2, Wc1, bc1, Wc2, bc2, strength, feat);
    hipLaunchKernelGGL(k_out, dim3(gO), dim3(BLK), 0, stream, relevant, feat, out, N, B);
}